// Round 9
// baseline (464.174 us; speedup 1.0000x reference)
//
#include <hip/hip_runtime.h>

typedef __attribute__((ext_vector_type(8))) short bf16x8;
typedef __attribute__((ext_vector_type(4))) float f32x4;

__device__ __forceinline__ unsigned short f2bf(float f) {
  unsigned int u = __builtin_bit_cast(unsigned int, f);
  unsigned int r = (u + 0x7FFFu + ((u >> 16) & 1u)) >> 16;  // RNE (finite inputs)
  return (unsigned short)r;
}

// Packed weight images: each wave's fragment load is ONE CONTIGUOUS 1KB burst
// (R8 lesson: [col][k] layout gathered 16B/lane at 128B stride -> 2x L2 overfetch).
// wm_img[i]: ushort[4096] = [tt(4)][sn(2)][q(4)][m(16)][j(8)]
//            value = Wm[i][k= sn*32+q*8+j][col= tt*16+m]
// wu_img:    ushort[8192] = [tt(4)][part(4, part3=pad0)][q(4)][m(16)][j(8)]
//            value = Wu[k= part*32+q*8+j][col= tt*16+m]   (k<96)
__global__ void prep_weights(const float* __restrict__ Wm,
                             const float* __restrict__ Wu,
                             unsigned short* __restrict__ wm_img,
                             unsigned short* __restrict__ wu_img) {
  const int i = blockIdx.x;
  const int tid = threadIdx.x;
  if (i < 26) {
    for (int e = tid; e < 4096; e += 256) {
      const int j = e & 7, m = (e >> 3) & 15, q = (e >> 7) & 3;
      const int sn = (e >> 9) & 1, tt = e >> 10;
      const int k = sn * 32 + q * 8 + j, col = tt * 16 + m;
      wm_img[i * 4096 + e] = f2bf(Wm[(i * 64 + k) * 64 + col]);
    }
  } else {
    for (int e = tid; e < 8192; e += 256) {
      const int j = e & 7, m = (e >> 3) & 15, q = (e >> 7) & 3;
      const int part = (e >> 9) & 3, tt = e >> 11;
      const int k = part * 32 + q * 8 + j, col = tt * 16 + m;
      wu_img[e] = (k < 96) ? f2bf(Wu[k * 64 + col]) : (unsigned short)0;
    }
  }
}

// Tile: 4x4x16 voxels. 512 threads = 8 waves; wave w owns TWO (tx,ty) columns.
// MFMA 16x16x32 bf16: A row = z (lane&15), k = channel ((lane>>4)*8+j).
//
// R9 structure: Wm NEVER in LDS. B-fragments live in registers, prefetched one
// offset ahead from the packed L2-resident image (in-place reload AFTER last
// MFMA use -> 32 live B regs, full-iteration load lead time). Main loop is
// BARRIER-FREE (x_lds/occ_lds read-only after prologue) -> waves free-run,
// L2 latency overlaps across 4 waves/SIMD. (R8 failed because the same L2
// loads were consumed in the SAME iteration: serial load->use chain.)
// LDS traffic/wave-iter: 4x ds_read_b128 (aS,aN) + 8x b32 (occ) ~= 94 cyc.
//
// Occupancy (R1-R7): unified VGPR+AGPR file; (512,4) caps total at 128.
// Tripwire: WRITE_SIZE must stay ==131072 KB (no scratch spills).
#define CB_STRIDE 10384  // 6*6*18*16 + 16B skew: staging lanes cb=0..3 distinct banks
__global__ __launch_bounds__(512, 4)
void voxconv_main(const float* __restrict__ x,
                  const float* __restrict__ occ,
                  const float* __restrict__ bm,
                  const float* __restrict__ bu,
                  const unsigned short* __restrict__ wm_img,
                  const unsigned short* __restrict__ wu_img,
                  float* __restrict__ out) {
  // x halo: [cb(4)][hx(6)][hy(6)][hz(18)][8ch] bf16 ; strides B: cb CB_STRIDE, hx 1728, hy 288, hz 16
  __shared__ __align__(16) unsigned short x_lds[2 * CB_STRIDE];  // 41536 B
  __shared__ __align__(16) float occ_lds[648];                   // [6][6][18] f32, 2592 B
  __shared__ __align__(16) unsigned short sc_lds[8192];          // epilogue scratch, 16384 B
  // total 60512 B -> LDS_Block_Size 60928 -> 2 blocks/CU

  const int tid  = (int)threadIdx.x;
  const int lane = tid & 63;
  const int w    = tid >> 6;
  const int q    = lane >> 4;   // k-chunk / quarter-wave
  const int m    = lane & 15;   // A row (z) / C col (within 16)

  const int id = (int)blockIdx.x;
  const int b  = id >> 10;
  const int ix = (id >> 6) & 15;
  const int iy = (id >> 2) & 15;
  const int iz = id & 3;
  const int x0 = ix << 2, y0 = iy << 2, z0 = iz << 4;

  // ---- stage x halo (648 voxels x 4 ch-chunks = 2592 items), f32 -> bf16 ----
  for (int it = 0; it < 6; ++it) {
    const int t = tid + it * 512;
    if (t < 2592) {
      const int cb = t & 3;
      const int v  = t >> 2;
      const int hz = v % 18;
      const int v2 = v / 18;
      const int hy = v2 % 6;
      const int hx = v2 / 6;
      const int X = (x0 + 63 + hx) & 63;
      const int Y = (y0 + 63 + hy) & 63;
      const int Z = (z0 + 63 + hz) & 63;
      const int vox = ((b * 64 + X) * 64 + Y) * 64 + Z;
      const float4* s4 = (const float4*)(x + vox * 32 + cb * 8);
      const float4 f0 = s4[0];
      const float4 f1 = s4[1];
      uint4 P;
      P.x = (unsigned)f2bf(f0.x) | ((unsigned)f2bf(f0.y) << 16);
      P.y = (unsigned)f2bf(f0.z) | ((unsigned)f2bf(f0.w) << 16);
      P.z = (unsigned)f2bf(f1.x) | ((unsigned)f2bf(f1.y) << 16);
      P.w = (unsigned)f2bf(f1.z) | ((unsigned)f2bf(f1.w) << 16);
      *(uint4*)((char*)x_lds + cb * CB_STRIDE + hx * 1728 + hy * 288 + hz * 16) = P;
    }
  }
  // ---- stage occ halo (f32) ----
  for (int t = tid; t < 648; t += 512) {
    const int hz = t % 18;
    const int v2 = t / 18;
    const int hy = v2 % 6;
    const int hx = v2 / 6;
    const int X = (x0 + 63 + hx) & 63;
    const int Y = (y0 + 63 + hy) & 63;
    const int Z = (z0 + 63 + hz) & 63;
    occ_lds[t] = occ[((b * 64 + X) * 64 + Y) * 64 + Z];
  }
  __syncthreads();  // x_lds / occ_lds read-only hereafter -> NO more barriers

  // ---- per-thread constant addresses (wave w owns columns g = 2w, 2w+1) ----
  int aSelf[2], occSelf[2], voxBase[2];
  #pragma unroll
  for (int gg = 0; gg < 2; ++gg) {
    const int g  = w * 2 + gg;
    const int tx = g >> 2, ty = g & 3;
    aSelf[gg]   = q * CB_STRIDE + (tx + 1) * 1728 + (ty + 1) * 288 + (1 + m) * 16;
    occSelf[gg] = (tx + 1) * 108 + (ty + 1) * 18 + 1 + q * 4;
    voxBase[gg] = ((b * 64 + (x0 + tx)) * 64 + (y0 + ty)) * 64 + z0;
  }
  int colIdx[4];
  #pragma unroll
  for (int tt = 0; tt < 4; ++tt) colIdx[tt] = tt * 16 + m;

  float agg[2][4][4];
  float den[2][4];
  #pragma unroll
  for (int gg = 0; gg < 2; ++gg)
    #pragma unroll
    for (int j = 0; j < 4; ++j) {
      den[gg][j] = 0.0f;
      #pragma unroll
      for (int tt = 0; tt < 4; ++tt) agg[gg][tt][j] = 0.0f;
    }

  // ---- register B-fragments: prologue load for offset 0 ----
  const char* wmb = (const char*)wm_img + (unsigned)lane * 16;
  bf16x8 bS[4], bN[4];
  float bmv[4];
  #pragma unroll
  for (int tt = 0; tt < 4; ++tt) {
    bS[tt]  = *(const bf16x8*)(wmb + tt * 2048);          // sn=0 (self)
    bN[tt]  = *(const bf16x8*)(wmb + tt * 2048 + 1024);   // sn=1 (nb)
    bmv[tt] = bm[colIdx[tt]];
  }

  // ---- 26-offset main loop: barrier-free, B prefetched 1 iter ahead ----
  #pragma unroll 1
  for (int i = 0; i < 26; ++i) {
    const int oi  = (i < 13) ? i : i + 1;          // skip (0,0,0)
    const int dxo = oi / 9 - 1;
    const int dyo = (oi / 3) % 3 - 1;
    const int dzo = oi % 3 - 1;
    // neighbor p-d (roll semantics: x_nb[p] = x[p-d])
    const int dA = -(dxo * 1728 + dyo * 288 + dzo * 16);
    const int dO = -(dxo * 108 + dyo * 18 + dzo);

    // A-frags + occ for both columns (LDS; shared across all tt)
    bf16x8 aS[2], aN[2];
    float on[2][4];
    #pragma unroll
    for (int gg = 0; gg < 2; ++gg) {
      aS[gg] = *(const bf16x8*)((const char*)x_lds + aSelf[gg]);
      aN[gg] = *(const bf16x8*)((const char*)x_lds + aSelf[gg] + dA);
      #pragma unroll
      for (int j = 0; j < 4; ++j) on[gg][j] = occ_lds[occSelf[gg] + dO + j];
    }

    #pragma unroll
    for (int tt = 0; tt < 4; ++tt) {
      #pragma unroll
      for (int gg = 0; gg < 2; ++gg) {
        f32x4 acc = {bmv[tt], bmv[tt], bmv[tt], bmv[tt]};
        acc = __builtin_amdgcn_mfma_f32_16x16x32_bf16(aS[gg], bS[tt], acc, 0, 0, 0);
        acc = __builtin_amdgcn_mfma_f32_16x16x32_bf16(aN[gg], bN[tt], acc, 0, 0, 0);
        #pragma unroll
        for (int j = 0; j < 4; ++j) {
          const float msg = fmaxf(acc[j], 0.0f);
          agg[gg][tt][j] = fmaf(msg, on[gg][j], agg[gg][tt][j]);
        }
      }
    }
    #pragma unroll
    for (int gg = 0; gg < 2; ++gg)
      #pragma unroll
      for (int j = 0; j < 4; ++j) den[gg][j] += on[gg][j];

    // in-place prefetch of offset i+1 (issued AFTER last use of bS/bN/bmv:
    // same 32 live regs, loads complete during next iter's LDS/VALU phase)
    if (i < 25) {
      const char* wn = wmb + (unsigned)(i + 1) * 8192;
      #pragma unroll
      for (int tt = 0; tt < 4; ++tt) {
        bS[tt]  = *(const bf16x8*)(wn + tt * 2048);
        bN[tt]  = *(const bf16x8*)(wn + tt * 2048 + 1024);
        bmv[tt] = bm[(i + 1) * 64 + colIdx[tt]];
      }
    }
  }

  // ---- agg /= (den + 1e-8) ----
  #pragma unroll
  for (int gg = 0; gg < 2; ++gg)
    #pragma unroll
    for (int j = 0; j < 4; ++j) {
      const float r = 1.0f / (den[gg][j] + 1e-8f);
      #pragma unroll
      for (int tt = 0; tt < 4; ++tt) agg[gg][tt][j] *= r;
    }

  // ---- update matmul: out = ([x|agg] @ Wu + bu) * occ_self ----
  char* scratch = (char*)sc_lds + w * 2048;  // per-wave 16 rows x 128B, private
  const int l7 = lane & 7;
  float buv[4];
  #pragma unroll
  for (int tt = 0; tt < 4; ++tt) buv[tt] = bu[colIdx[tt]];

  const char* wub = (const char*)wu_img + (unsigned)lane * 16;
  #pragma unroll
  for (int gg = 0; gg < 2; ++gg) {
    // C-layout agg -> bf16 A-layout scratch (row-XOR swizzle); per-wave
    // private, wave-synchronous: no barrier needed.
    #pragma unroll
    for (int tt = 0; tt < 4; ++tt) {
      const int colhi = tt * 2 + ((lane >> 3) & 1);  // col>>3
      #pragma unroll
      for (int j = 0; j < 4; ++j) {
        const int row = q * 4 + j;
        const int bo = row * 128 + ((colhi ^ (row & 7)) << 4) + l7 * 2;
        *(unsigned short*)(scratch + bo) = f2bf(agg[gg][tt][j]);
      }
    }
    const bf16x8 ax  = *(const bf16x8*)((const char*)x_lds + aSelf[gg]);
    const bf16x8 ag0 = *(const bf16x8*)(scratch + m * 128 + ((q ^ (m & 7)) << 4));
    const bf16x8 ag1 = *(const bf16x8*)(scratch + m * 128 + (((4 + q) ^ (m & 7)) << 4));
    float os[4];
    #pragma unroll
    for (int j = 0; j < 4; ++j) os[j] = occ_lds[occSelf[gg] + j];
    // Wu fragments per-tt from packed L2 image (contiguous 1KB wave bursts)
    #pragma unroll
    for (int tt = 0; tt < 4; ++tt) {
      const bf16x8 bux  = *(const bf16x8*)(wub + tt * 4096);         // k 0..31 (x)
      const bf16x8 bua0 = *(const bf16x8*)(wub + tt * 4096 + 1024);  // k 32..63
      const bf16x8 bua1 = *(const bf16x8*)(wub + tt * 4096 + 2048);  // k 64..95
      f32x4 acc = {buv[tt], buv[tt], buv[tt], buv[tt]};
      acc = __builtin_amdgcn_mfma_f32_16x16x32_bf16(ax,  bux,  acc, 0, 0, 0);
      acc = __builtin_amdgcn_mfma_f32_16x16x32_bf16(ag0, bua0, acc, 0, 0, 0);
      acc = __builtin_amdgcn_mfma_f32_16x16x32_bf16(ag1, bua1, acc, 0, 0, 0);
      #pragma unroll
      for (int j = 0; j < 4; ++j) {
        out[(voxBase[gg] + q * 4 + j) * 64 + colIdx[tt]] = acc[j] * os[j];
      }
    }
  }
}

extern "C" void kernel_launch(void* const* d_in, const int* in_sizes, int n_in,
                              void* d_out, int out_size, void* d_ws, size_t ws_size,
                              hipStream_t stream) {
  const float* x   = (const float*)d_in[0];
  const float* occ = (const float*)d_in[1];
  const float* Wm  = (const float*)d_in[2];
  const float* bm  = (const float*)d_in[3];
  const float* Wu  = (const float*)d_in[4];
  const float* bu  = (const float*)d_in[5];
  float* out = (float*)d_out;

  unsigned short* wm_img = (unsigned short*)d_ws;        // 26*4096 ushort = 208 KB
  unsigned short* wu_img = wm_img + 26 * 4096;           // 8192 ushort   =  16 KB

  prep_weights<<<27, 256, 0, stream>>>(Wm, Wu, wm_img, wu_img);
  voxconv_main<<<2048, 512, 0, stream>>>(x, occ, bm, bu, wm_img, wu_img, out);
}

// Round 10
// 193.902 us; speedup vs baseline: 2.3939x; 2.3939x over previous
//
#include <hip/hip_runtime.h>

typedef __attribute__((ext_vector_type(8))) short bf16x8;
typedef __attribute__((ext_vector_type(4))) float f32x4;

__device__ __forceinline__ unsigned short f2bf(float f) {
  unsigned int u = __builtin_bit_cast(unsigned int, f);
  unsigned int r = (u + 0x7FFFu + ((u >> 16) & 1u)) >> 16;  // RNE (finite inputs)
  return (unsigned short)r;
}

// Packed weight images: each wave's fragment load is ONE CONTIGUOUS 1KB burst.
// wm_img[i]: ushort[4096] = [tt(4)][sn(2)][q(4)][m(16)][j(8)]
//            value = Wm[i][k= sn*32+q*8+j][col= tt*16+m]
//   -> phase g = i*4+tt reads bytes [g*2048, g*2048+2048): LINEAR in g.
// wu_img:    ushort[8192] = [tt(4)][part(4, part3=pad0)][q(4)][m(16)][j(8)]
//            value = Wu[k= part*32+q*8+j][col= tt*16+m]   (k<96)
__global__ void prep_weights(const float* __restrict__ Wm,
                             const float* __restrict__ Wu,
                             unsigned short* __restrict__ wm_img,
                             unsigned short* __restrict__ wu_img) {
  const int i = blockIdx.x;
  const int tid = threadIdx.x;
  if (i < 26) {
    for (int e = tid; e < 4096; e += 256) {
      const int j = e & 7, m = (e >> 3) & 15, q = (e >> 7) & 3;
      const int sn = (e >> 9) & 1, tt = e >> 10;
      const int k = sn * 32 + q * 8 + j, col = tt * 16 + m;
      wm_img[i * 4096 + e] = f2bf(Wm[(i * 64 + k) * 64 + col]);
    }
  } else {
    for (int e = tid; e < 8192; e += 256) {
      const int j = e & 7, m = (e >> 3) & 15, q = (e >> 7) & 3;
      const int part = (e >> 9) & 3, tt = e >> 11;
      const int k = part * 32 + q * 8 + j, col = tt * 16 + m;
      wu_img[e] = (k < 96) ? f2bf(Wu[k * 64 + col]) : (unsigned short)0;
    }
  }
}

// R10: barrier-free main loop; B-frags from packed L2 image with PHASE-level
// software pipelining. The 26x4 (offset x tt) space is linear in g=i*4+tt:
// each phase consumes 2KB (bS,bN) + 1 bm scalar at address g*2048 and
// prefetches phase g+1 into the OTHER statically-named register set (A/B
// ping-pong; even/odd phases -> compile-time set choice, no dynamic arrays).
// Live B regs = 16 (R9's 32-live back-edge caused ~40-reg spill = 305MB
// scratch; R8's no-lead same-iter loads starved MFMA at 10%). LDS per
// wave-iter: 6 b128 (aS,aN) + 8 b32 (occ) ~= 95cyc vs R7's 143, and no
// 16-wave barrier lockstep re-aligning LDS bursts.
//
// Occupancy (R1-R9): (512,4) => ~64 non-acc regs usable; WRITE_SIZE==131072
// is the no-spill tripwire. LDS 60.5KB -> 2 blocks/CU (128KB pool).
#define CB_STRIDE 10384  // 6*6*18*16 + 16B skew
__global__ __launch_bounds__(512, 4)
void voxconv_main(const float* __restrict__ x,
                  const float* __restrict__ occ,
                  const float* __restrict__ bm,
                  const float* __restrict__ bu,
                  const unsigned short* __restrict__ wm_img,
                  const unsigned short* __restrict__ wu_img,
                  float* __restrict__ out) {
  // x halo: [cb(4)][hx(6)][hy(6)][hz(18)][8ch] bf16 ; strides B: cb CB_STRIDE, hx 1728, hy 288, hz 16
  __shared__ __align__(16) unsigned short x_lds[2 * CB_STRIDE];  // 41536 B
  __shared__ __align__(16) float occ_lds[648];                   // [6][6][18] f32, 2592 B
  __shared__ __align__(16) unsigned short sc_lds[8192];          // epilogue scratch, 16384 B
  // total 60512 B -> LDS_Block_Size 60928 -> 2 blocks/CU

  const int tid  = (int)threadIdx.x;
  const int lane = tid & 63;
  const int w    = tid >> 6;
  const int q    = lane >> 4;   // k-chunk / quarter-wave
  const int m    = lane & 15;   // A row (z) / C col (within 16)

  const int id = (int)blockIdx.x;
  const int b  = id >> 10;
  const int ix = (id >> 6) & 15;
  const int iy = (id >> 2) & 15;
  const int iz = id & 3;
  const int x0 = ix << 2, y0 = iy << 2, z0 = iz << 4;

  // ---- stage x halo (648 voxels x 4 ch-chunks = 2592 items), f32 -> bf16 ----
  for (int it = 0; it < 6; ++it) {
    const int t = tid + it * 512;
    if (t < 2592) {
      const int cb = t & 3;
      const int v  = t >> 2;
      const int hz = v % 18;
      const int v2 = v / 18;
      const int hy = v2 % 6;
      const int hx = v2 / 6;
      const int X = (x0 + 63 + hx) & 63;
      const int Y = (y0 + 63 + hy) & 63;
      const int Z = (z0 + 63 + hz) & 63;
      const int vox = ((b * 64 + X) * 64 + Y) * 64 + Z;
      const float4* s4 = (const float4*)(x + vox * 32 + cb * 8);
      const float4 f0 = s4[0];
      const float4 f1 = s4[1];
      uint4 P;
      P.x = (unsigned)f2bf(f0.x) | ((unsigned)f2bf(f0.y) << 16);
      P.y = (unsigned)f2bf(f0.z) | ((unsigned)f2bf(f0.w) << 16);
      P.z = (unsigned)f2bf(f1.x) | ((unsigned)f2bf(f1.y) << 16);
      P.w = (unsigned)f2bf(f1.z) | ((unsigned)f2bf(f1.w) << 16);
      *(uint4*)((char*)x_lds + cb * CB_STRIDE + hx * 1728 + hy * 288 + hz * 16) = P;
    }
  }
  // ---- stage occ halo (f32) ----
  for (int t = tid; t < 648; t += 512) {
    const int hz = t % 18;
    const int v2 = t / 18;
    const int hy = v2 % 6;
    const int hx = v2 / 6;
    const int X = (x0 + 63 + hx) & 63;
    const int Y = (y0 + 63 + hy) & 63;
    const int Z = (z0 + 63 + hz) & 63;
    occ_lds[t] = occ[((b * 64 + X) * 64 + Y) * 64 + Z];
  }
  __syncthreads();  // x_lds / occ_lds read-only hereafter -> NO more barriers

  // ---- per-thread constant addresses (wave w owns columns g = 2w, 2w+1) ----
  int aSelf[2], occSelf[2];
  #pragma unroll
  for (int gg = 0; gg < 2; ++gg) {
    const int g  = w * 2 + gg;
    const int tx = g >> 2, ty = g & 3;
    aSelf[gg]   = q * CB_STRIDE + (tx + 1) * 1728 + (ty + 1) * 288 + (1 + m) * 16;
    occSelf[gg] = (tx + 1) * 108 + (ty + 1) * 18 + 1 + q * 4;
  }

  float agg[2][4][4];
  float den[2][4];
  #pragma unroll
  for (int gg = 0; gg < 2; ++gg)
    #pragma unroll
    for (int j = 0; j < 4; ++j) {
      den[gg][j] = 0.0f;
      #pragma unroll
      for (int tt = 0; tt < 4; ++tt) agg[gg][tt][j] = 0.0f;
    }

  // ---- B ping-pong register sets; prologue load of phase 0 ----
  const char* wmb = (const char*)wm_img + (unsigned)lane * 16;
  bf16x8 bSA, bNA, bSB, bNB;
  float bmA, bmB;
  bSA = *(const bf16x8*)(wmb);
  bNA = *(const bf16x8*)(wmb + 1024);
  bmA = bm[m];

// One phase: prefetch phase (i*4+TT+1) into the NEXT set (linear address
// +2048; works across the i boundary since (i,3)+1 == (i+1,0)), then 4 MFMAs
// using the CURRENT set, then relu + occ-gated accumulate.
#define PHASE(TT, BSU, BNU, BMU, BSN, BNN, BMN, GUARD)                         \
  {                                                                            \
    if (GUARD) {                                                               \
      const char* np_ = wmb + ((unsigned)i * 8192u + (unsigned)(TT + 1) * 2048u); \
      BSN = *(const bf16x8*)np_;                                               \
      BNN = *(const bf16x8*)(np_ + 1024);                                      \
      BMN = bm[(i * 4 + TT + 1) * 16 + m];                                     \
    }                                                                          \
    _Pragma("unroll")                                                          \
    for (int gg = 0; gg < 2; ++gg) {                                           \
      f32x4 acc = {BMU, BMU, BMU, BMU};                                        \
      acc = __builtin_amdgcn_mfma_f32_16x16x32_bf16(aS[gg], BSU, acc, 0, 0, 0);\
      acc = __builtin_amdgcn_mfma_f32_16x16x32_bf16(aN[gg], BNU, acc, 0, 0, 0);\
      _Pragma("unroll")                                                        \
      for (int j = 0; j < 4; ++j) {                                            \
        const float msg = fmaxf(acc[j], 0.0f);                                 \
        agg[gg][TT][j] = fmaf(msg, on[gg][j], agg[gg][TT][j]);                 \
      }                                                                        \
    }                                                                          \
  }

  // ---- 26-offset main loop: barrier-free, phase-pipelined B ----
  #pragma unroll 1
  for (int i = 0; i < 26; ++i) {
    const int oi  = (i < 13) ? i : i + 1;          // skip (0,0,0)
    const int dxo = oi / 9 - 1;
    const int dyo = (oi / 3) % 3 - 1;
    const int dzo = oi % 3 - 1;
    // neighbor p-d (roll semantics: x_nb[p] = x[p-d])
    const int dA = -(dxo * 1728 + dyo * 288 + dzo * 16);
    const int dO = -(dxo * 108 + dyo * 18 + dzo);

    // A-frags + occ for both columns (LDS; shared across the 4 phases)
    bf16x8 aS[2], aN[2];
    float on[2][4];
    #pragma unroll
    for (int gg = 0; gg < 2; ++gg) {
      aS[gg] = *(const bf16x8*)((const char*)x_lds + aSelf[gg]);
      aN[gg] = *(const bf16x8*)((const char*)x_lds + aSelf[gg] + dA);
      #pragma unroll
      for (int j = 0; j < 4; ++j) on[gg][j] = occ_lds[occSelf[gg] + dO + j];
    }
    #pragma unroll
    for (int gg = 0; gg < 2; ++gg)
      #pragma unroll
      for (int j = 0; j < 4; ++j) den[gg][j] += on[gg][j];

    PHASE(0, bSA, bNA, bmA, bSB, bNB, bmB, true)
    PHASE(1, bSB, bNB, bmB, bSA, bNA, bmA, true)
    PHASE(2, bSA, bNA, bmA, bSB, bNB, bmB, true)
    PHASE(3, bSB, bNB, bmB, bSA, bNA, bmA, (i < 25))
  }
#undef PHASE

  // ---- agg /= (den + 1e-8) ----
  #pragma unroll
  for (int gg = 0; gg < 2; ++gg)
    #pragma unroll
    for (int j = 0; j < 4; ++j) {
      const float r = 1.0f / (den[gg][j] + 1e-8f);
      #pragma unroll
      for (int tt = 0; tt < 4; ++tt) agg[gg][tt][j] *= r;
    }

  // ---- update matmul: out = ([x|agg] @ Wu + bu) * occ_self ----
  char* scratch = (char*)sc_lds + w * 2048;  // per-wave 16 rows x 128B, private
  const int l7 = lane & 7;
  int colIdx[4];
  #pragma unroll
  for (int tt = 0; tt < 4; ++tt) colIdx[tt] = tt * 16 + m;
  int voxBase[2];
  #pragma unroll
  for (int gg = 0; gg < 2; ++gg) {
    const int g  = w * 2 + gg;
    const int tx = g >> 2, ty = g & 3;
    voxBase[gg] = ((b * 64 + (x0 + tx)) * 64 + (y0 + ty)) * 64 + z0;
  }
  float buv[4];
  #pragma unroll
  for (int tt = 0; tt < 4; ++tt) buv[tt] = bu[colIdx[tt]];

  const char* wub = (const char*)wu_img + (unsigned)lane * 16;
  #pragma unroll
  for (int gg = 0; gg < 2; ++gg) {
    // C-layout agg -> bf16 A-layout scratch (row-XOR swizzle); per-wave
    // private, wave-synchronous: no barrier needed.
    #pragma unroll
    for (int tt = 0; tt < 4; ++tt) {
      const int colhi = tt * 2 + ((lane >> 3) & 1);  // col>>3
      #pragma unroll
      for (int j = 0; j < 4; ++j) {
        const int row = q * 4 + j;
        const int bo = row * 128 + ((colhi ^ (row & 7)) << 4) + l7 * 2;
        *(unsigned short*)(scratch + bo) = f2bf(agg[gg][tt][j]);
      }
    }
    const bf16x8 ax  = *(const bf16x8*)((const char*)x_lds + aSelf[gg]);
    const bf16x8 ag0 = *(const bf16x8*)(scratch + m * 128 + ((q ^ (m & 7)) << 4));
    const bf16x8 ag1 = *(const bf16x8*)(scratch + m * 128 + (((4 + q) ^ (m & 7)) << 4));
    float os[4];
    #pragma unroll
    for (int j = 0; j < 4; ++j) os[j] = occ_lds[occSelf[gg] + j];
    // Wu fragments per-tt from packed L2 image (contiguous 1KB wave bursts)
    #pragma unroll
    for (int tt = 0; tt < 4; ++tt) {
      const bf16x8 bux  = *(const bf16x8*)(wub + tt * 4096);         // k 0..31 (x)
      const bf16x8 bua0 = *(const bf16x8*)(wub + tt * 4096 + 1024);  // k 32..63
      const bf16x8 bua1 = *(const bf16x8*)(wub + tt * 4096 + 2048);  // k 64..95
      f32x4 acc = {buv[tt], buv[tt], buv[tt], buv[tt]};
      acc = __builtin_amdgcn_mfma_f32_16x16x32_bf16(ax,  bux,  acc, 0, 0, 0);
      acc = __builtin_amdgcn_mfma_f32_16x16x32_bf16(ag0, bua0, acc, 0, 0, 0);
      acc = __builtin_amdgcn_mfma_f32_16x16x32_bf16(ag1, bua1, acc, 0, 0, 0);
      #pragma unroll
      for (int j = 0; j < 4; ++j) {
        out[(voxBase[gg] + q * 4 + j) * 64 + colIdx[tt]] = acc[j] * os[j];
      }
    }
  }
}

extern "C" void kernel_launch(void* const* d_in, const int* in_sizes, int n_in,
                              void* d_out, int out_size, void* d_ws, size_t ws_size,
                              hipStream_t stream) {
  const float* x   = (const float*)d_in[0];
  const float* occ = (const float*)d_in[1];
  const float* Wm  = (const float*)d_in[2];
  const float* bm  = (const float*)d_in[3];
  const float* Wu  = (const float*)d_in[4];
  const float* bu  = (const float*)d_in[5];
  float* out = (float*)d_out;

  unsigned short* wm_img = (unsigned short*)d_ws;        // 26*4096 ushort = 208 KB
  unsigned short* wu_img = wm_img + 26 * 4096;           // 8192 ushort   =  16 KB

  prep_weights<<<27, 256, 0, stream>>>(Wm, Wu, wm_img, wu_img);
  voxconv_main<<<2048, 512, 0, stream>>>(x, occ, bm, bu, wm_img, wu_img, out);
}